// Round 14
// baseline (270.764 us; speedup 1.0000x reference)
//
#include <hip/hip_runtime.h>
#include <math.h>

#define NTREES 512
#define DEPTH  10
#define NPT    1023
#define NTOT   (NTREES * NPT)   // 523776
#define H      64
#define PART_SLOTS 32256        // wave partials for levels 9(leaf)..4

typedef __attribute__((ext_vector_type(8))) short bf16x8;
typedef __attribute__((ext_vector_type(4))) float f32x4;

// v_rcp_f32 (1-ulp approx) instead of IEEE divide: saves ~14 VALU inst per gate.
__device__ __forceinline__ float sigm(float x)  { return __builtin_amdgcn_rcpf(1.0f + __expf(-x)); }
__device__ __forceinline__ float ftanh(float x) { return fmaf(-2.0f, __builtin_amdgcn_rcpf(__expf(2.0f * x) + 1.0f), 1.0f); }

__device__ __forceinline__ unsigned short bf_hi(float f) {
    unsigned u = __float_as_uint(f);
    return (unsigned short)((u + 0x7fffu + ((u >> 16) & 1u)) >> 16);
}
__device__ __forceinline__ float bf_f(unsigned short h) {
    return __uint_as_float(((unsigned)h) << 16);
}
__device__ __forceinline__ void split8(const float v[8], bf16x8& hi, bf16x8& lo) {
    #pragma unroll
    for (int e = 0; e < 8; ++e) {
        unsigned short hh = bf_hi(v[e]);
        hi[e] = (short)hh;
        lo[e] = (short)bf_hi(v[e] - bf_f(hh));
    }
}

#define MFMA(a, b, c) __builtin_amdgcn_mfma_f32_16x16x32_bf16((a), (b), (c), 0, 0, 0)

// Direct global->LDS DMA, 16B per lane. Per-wave dest = uniform base + lane*16
// (HW-supported layout); in-flight loads hold NO VGPRs; the next
// __syncthreads() (vmcnt(0) drain) completes them.
__device__ __forceinline__ void gl_lds16(const void* g, void* s) {
    __builtin_amdgcn_global_load_lds(
        (const __attribute__((address_space(1))) unsigned*)g,
        (__attribute__((address_space(3))) unsigned*)s, 16, 0, 0);
}

// ---- B prep (layout unchanged from rounds 3..13) ----
__global__ void prep_b(const float* __restrict__ w_iou, const float* __restrict__ u_iou,
                       const float* __restrict__ w_f,  const float* __restrict__ u_f,
                       unsigned short* __restrict__ B)
{
    int idx  = blockIdx.x * 256 + threadIdx.x;   // 0..65535
    int unit = idx >> 3;
    int e    = idx & 7;
    int l    = unit & 63;
    float v;
    int hl;
    if (unit < 6144) {
        int sp = (unit >= 3072) ? 1 : 0;
        int r  = unit - sp * 3072;
        int q  = r >> 6;
        hl     = q & 1;
        int ts = q >> 1;
        int s_ = ts & 1;
        int t  = ts >> 1;
        int s  = sp * 2 + s_;
        int col = t * 16 + (l & 15);
        int k   = 32 * s + 8 * (l >> 4) + e;
        v = (k < 64) ? w_iou[col * H + k] : u_iou[col * H + (k - 64)];
    } else {
        int r  = unit - 6144;
        int q  = r >> 6;
        hl     = q & 1;
        int xu = (q >> 1) & 1;
        int ts = q >> 2;
        int s  = ts & 1;
        int t  = ts >> 1;
        int col = t * 16 + (l & 15);
        int k   = 32 * s + 8 * (l >> 4) + e;
        v = xu ? u_f[col * H + k] : w_f[col * H + k];
    }
    unsigned short hv = bf_hi(v);
    B[idx] = hl ? bf_hi(v - bf_f(hv)) : hv;
}

// Per-wave pooling partial: psum[t] summed across the four 16-lane groups.
__device__ __forceinline__ void store_partial(float psum[4], int l, int wid,
                                              float* __restrict__ partw)
{
    #pragma unroll
    for (int t = 0; t < 4; ++t) {
        float v = psum[t];
        v += __shfl_xor(v, 16);
        v += __shfl_xor(v, 32);
        if (l < 16) partw[(size_t)wid * H + 16 * t + l] = v;
    }
}

// ---- Leaves: 4 waves/block, 16 nodes/wave; iou-x staged as two 24KB halves
// through a ping-pong pair: second half's DMA issues before first half's MFMAs.
__global__ __launch_bounds__(256, 3)
void leaf_mfma(const float* __restrict__ feat, const unsigned short* __restrict__ Braw,
               const float* __restrict__ b_iou,
               float* __restrict__ h, float* __restrict__ c,
               float* __restrict__ partw, int do_part)
{
    __shared__ bf16x8 Bs[3072];                  // buf0 = [0,1536), buf1 = [1536,3072)
    int tid = threadIdx.x;
    int l   = tid & 63;
    int w   = tid >> 6;
    int base = blockIdx.x * 64 + w * 16;
    int g    = base + (l & 15);
    int nrow = (g >> 9) * NPT + 511 + (g & 511);
    int ko   = 8 * (l >> 4);

    const float* fb = feat + (size_t)nrow * H + ko;
    float4 fr0 = *(const float4*)(fb);
    float4 fr1 = *(const float4*)(fb + 4);
    float4 fr2 = *(const float4*)(fb + 32);
    float4 fr3 = *(const float4*)(fb + 36);

    const bf16x8* Bg = (const bf16x8*)Braw;
    for (int u = tid; u < 1536; u += 256) gl_lds16(Bg + u, Bs + u);          // t=0..5
    __syncthreads();
    for (int u = tid; u < 1536; u += 256) gl_lds16(Bg + 1536 + u, Bs + 1536 + u); // t=6..11 in flight

    bf16x8 fh[2], fl[2];
    { float v[8] = {fr0.x,fr0.y,fr0.z,fr0.w,fr1.x,fr1.y,fr1.z,fr1.w}; split8(v, fh[0], fl[0]); }
    { float v[8] = {fr2.x,fr2.y,fr2.z,fr2.w,fr3.x,fr3.y,fr3.z,fr3.w}; split8(v, fh[1], fl[1]); }

    f32x4 acc[12];
    #pragma unroll
    for (int t = 0; t < 12; ++t) acc[t] = (f32x4){0.f,0.f,0.f,0.f};
    __builtin_amdgcn_s_setprio(1);
    #pragma unroll
    for (int t = 0; t < 6; ++t) {
        #pragma unroll
        for (int s = 0; s < 2; ++s) {
            bf16x8 bh = Bs[((t * 2 + s) * 2 + 0) * 64 + l];
            bf16x8 bl = Bs[((t * 2 + s) * 2 + 1) * 64 + l];
            acc[t] = MFMA(fh[s], bh, acc[t]);
            acc[t] = MFMA(fh[s], bl, acc[t]);
            acc[t] = MFMA(fl[s], bh, acc[t]);
        }
    }
    __builtin_amdgcn_s_setprio(0);
    __syncthreads();                              // drains second-half DMA
    __builtin_amdgcn_s_setprio(1);
    #pragma unroll
    for (int t = 6; t < 12; ++t) {
        int tt = t - 6;
        #pragma unroll
        for (int s = 0; s < 2; ++s) {
            bf16x8 bh = Bs[1536 + ((tt * 2 + s) * 2 + 0) * 64 + l];
            bf16x8 bl = Bs[1536 + ((tt * 2 + s) * 2 + 1) * 64 + l];
            acc[t] = MFMA(fh[s], bh, acc[t]);
            acc[t] = MFMA(fh[s], bl, acc[t]);
            acc[t] = MFMA(fl[s], bh, acc[t]);
        }
    }
    __builtin_amdgcn_s_setprio(0);

    int colb = l & 15;
    float psum[4] = {0.f, 0.f, 0.f, 0.f};
    #pragma unroll
    for (int r = 0; r < 4; ++r) {
        int gr = base + (l >> 4) * 4 + r;
        int nr = (gr >> 9) * NPT + 511 + (gr & 511);
        #pragma unroll
        for (int t = 0; t < 4; ++t) {
            int j = 16 * t + colb;
            float ai = acc[t][r]     + b_iou[j];
            float ao = acc[4 + t][r] + b_iou[64 + j];
            float au = acc[8 + t][r] + b_iou[128 + j];
            float cv = sigm(ai) * ftanh(au);
            float hval = sigm(ao) * ftanh(cv);
            c[(size_t)nr * H + j] = cv;
            h[(size_t)nr * H + j] = hval;
            psum[t] += hval;
        }
    }
    if (do_part) store_partial(psum, l, blockIdx.x * 4 + w, partw);
}

// ---- Internal levels (lvl 8..4): 4 waves/block, 16 nodes/wave.
// B staged as SIX <=24KB chunks (Fx, Fu, I1a, I1b, I2a, I2b) ping-ponged
// through two 24KB LDS halves: chunk k+1's DMA is issued BEFORE chunk k's
// MFMAs, so staging latency hides under compute. Per-accumulator MFMA order
// identical to rounds 10-13 -> bit-identical output.
__global__ __launch_bounds__(256, 3)
void internal_mfma(const float* __restrict__ feat, const unsigned short* __restrict__ Braw,
                   const float* __restrict__ b_iou, const float* __restrict__ b_f,
                   float* __restrict__ h, float* __restrict__ c, int lvl,
                   float* __restrict__ partw, int woff)
{
    __shared__ bf16x8 Bs[3072];                  // buf0 = [0,1536), buf1 = [1536,3072)
    int tid = threadIdx.x;
    int l   = tid & 63;
    int w   = tid >> 6;
    int m   = 1 << lvl;
    int base  = blockIdx.x * 64 + w * 16;
    int g     = base + (l & 15);
    int tree  = g >> lvl, i = g & (m - 1);
    int local = (m - 1) + i;
    int nrow  = tree * NPT + local;
    int crow0 = tree * NPT + 2 * local + 1;
    int ko    = 8 * (l >> 4);
    int colb  = l & 15;

    // issue all A loads first; latency hides under staging + barrier
    const float* fb  = feat + (size_t)nrow * H + ko;
    float4 fr0 = *(const float4*)(fb);
    float4 fr1 = *(const float4*)(fb + 4);
    float4 fr2 = *(const float4*)(fb + 32);
    float4 fr3 = *(const float4*)(fb + 36);
    const float* h0b = h + (size_t)crow0 * H + ko;
    const float* h1b = h0b + H;
    float4 a00 = *(const float4*)(h0b);
    float4 a01 = *(const float4*)(h0b + 4);
    float4 a02 = *(const float4*)(h0b + 32);
    float4 a03 = *(const float4*)(h0b + 36);
    float4 a10 = *(const float4*)(h1b);
    float4 a11 = *(const float4*)(h1b + 4);
    float4 a12 = *(const float4*)(h1b + 32);
    float4 a13 = *(const float4*)(h1b + 36);

    const bf16x8* Bg = (const bf16x8*)Braw;
    // chunk Fx (fx hi/lo, 1024 units = 16KB) -> buf0.
    // global: 6144 + ((ts*4) + hl)*64 + l ; LDS: (ts*2+hl)*64 + l
    for (int u = tid; u < 1024; u += 256) {
        int q = u >> 6, li = u & 63;
        gl_lds16(Bg + 6144 + ((q >> 1) * 4 + (q & 1)) * 64 + li, Bs + u);
    }
    __syncthreads();
    // chunk Fu (fu hi/lo) -> buf1 : in flight under splits + P0
    for (int u = tid; u < 1024; u += 256) {
        int q = u >> 6, li = u & 63;
        gl_lds16(Bg + 6144 + ((q >> 1) * 4 + 2 + (q & 1)) * 64 + li, Bs + 1536 + u);
    }

    bf16x8 fh[2], fl[2], sh[2], sl[2], zh[2], zl[2];
    { float v[8] = {fr0.x,fr0.y,fr0.z,fr0.w,fr1.x,fr1.y,fr1.z,fr1.w}; split8(v, fh[0], fl[0]); }
    { float v[8] = {fr2.x,fr2.y,fr2.z,fr2.w,fr3.x,fr3.y,fr3.z,fr3.w}; split8(v, fh[1], fl[1]); }
    {
        float v0[8] = {a00.x,a00.y,a00.z,a00.w,a01.x,a01.y,a01.z,a01.w};
        float v1[8] = {a10.x,a10.y,a10.z,a10.w,a11.x,a11.y,a11.z,a11.w};
        float vs[8];
        #pragma unroll
        for (int e = 0; e < 8; ++e) vs[e] = v0[e] + v1[e];
        split8(v0, zh[0], zl[0]); split8(vs, sh[0], sl[0]);
    }
    {
        float v0[8] = {a02.x,a02.y,a02.z,a02.w,a03.x,a03.y,a03.z,a03.w};
        float v1[8] = {a12.x,a12.y,a12.z,a12.w,a13.x,a13.y,a13.z,a13.w};
        float vs[8];
        #pragma unroll
        for (int e = 0; e < 8; ++e) vs[e] = v0[e] + v1[e];
        split8(v0, zh[1], zl[1]); split8(vs, sh[1], sl[1]);
    }

    // P0: ax accumulators from Fx (buf0)
    f32x4 axs[4];
    __builtin_amdgcn_s_setprio(1);
    #pragma unroll
    for (int t = 0; t < 4; ++t) {
        f32x4 ax = (f32x4){0.f,0.f,0.f,0.f};
        #pragma unroll
        for (int s = 0; s < 2; ++s) {
            bf16x8 bxh = Bs[((t * 2 + s) * 2 + 0) * 64 + l];
            bf16x8 bxl = Bs[((t * 2 + s) * 2 + 1) * 64 + l];
            ax = MFMA(fh[s], bxh, ax);  ax = MFMA(fh[s], bxl, ax);  ax = MFMA(fl[s], bxh, ax);
        }
        axs[t] = ax;
    }
    __builtin_amdgcn_s_setprio(0);
    __syncthreads();                             // drains Fu
    // chunk I1a (iou-x t=0..5) -> buf0 : in flight under P1
    for (int u = tid; u < 1536; u += 256) gl_lds16(Bg + u, Bs + u);

    // P1: as_/az from Fu (buf1), then forget gates
    float f0[4][4], f1[4][4];
    __builtin_amdgcn_s_setprio(1);
    #pragma unroll
    for (int t = 0; t < 4; ++t) {
        f32x4 as_ = (f32x4){0.f,0.f,0.f,0.f};
        f32x4 az  = (f32x4){0.f,0.f,0.f,0.f};
        #pragma unroll
        for (int s = 0; s < 2; ++s) {
            bf16x8 buh = Bs[1536 + ((t * 2 + s) * 2 + 0) * 64 + l];
            bf16x8 bul = Bs[1536 + ((t * 2 + s) * 2 + 1) * 64 + l];
            as_ = MFMA(sh[s], buh, as_); as_ = MFMA(sh[s], bul, as_); as_ = MFMA(sl[s], buh, as_);
            az  = MFMA(zh[s], buh, az);  az  = MFMA(zh[s], bul, az);  az  = MFMA(zl[s], buh, az);
        }
        #pragma unroll
        for (int r = 0; r < 4; ++r) {
            float afx = axs[t][r] + b_f[16 * t + colb];
            f0[t][r] = sigm(afx + az[r]);
            f1[t][r] = sigm(afx + (as_[r] - az[r]));
        }
    }
    __builtin_amdgcn_s_setprio(0);
    __syncthreads();                             // drains I1a
    // chunk I1b (iou-x t=6..11) -> buf1 : in flight under P2
    for (int u = tid; u < 1536; u += 256) gl_lds16(Bg + 1536 + u, Bs + 1536 + u);

    f32x4 acc[12];
    #pragma unroll
    for (int t = 0; t < 12; ++t) acc[t] = (f32x4){0.f,0.f,0.f,0.f};

    // P2: acc[0..5] x-contribution from buf0
    __builtin_amdgcn_s_setprio(1);
    #pragma unroll
    for (int t = 0; t < 6; ++t) {
        #pragma unroll
        for (int s = 0; s < 2; ++s) {
            bf16x8 bh = Bs[((t * 2 + s) * 2 + 0) * 64 + l];
            bf16x8 bl = Bs[((t * 2 + s) * 2 + 1) * 64 + l];
            acc[t] = MFMA(fh[s], bh, acc[t]);
            acc[t] = MFMA(fh[s], bl, acc[t]);
            acc[t] = MFMA(fl[s], bh, acc[t]);
        }
    }
    __builtin_amdgcn_s_setprio(0);
    __syncthreads();                             // drains I1b
    // chunk I2a (iou-hs t=0..5) -> buf0 : in flight under P3
    for (int u = tid; u < 1536; u += 256) gl_lds16(Bg + 3072 + u, Bs + u);

    // P3: acc[6..11] x-contribution from buf1
    __builtin_amdgcn_s_setprio(1);
    #pragma unroll
    for (int t = 6; t < 12; ++t) {
        int tt = t - 6;
        #pragma unroll
        for (int s = 0; s < 2; ++s) {
            bf16x8 bh = Bs[1536 + ((tt * 2 + s) * 2 + 0) * 64 + l];
            bf16x8 bl = Bs[1536 + ((tt * 2 + s) * 2 + 1) * 64 + l];
            acc[t] = MFMA(fh[s], bh, acc[t]);
            acc[t] = MFMA(fh[s], bl, acc[t]);
            acc[t] = MFMA(fl[s], bh, acc[t]);
        }
    }
    __builtin_amdgcn_s_setprio(0);
    __syncthreads();                             // drains I2a
    // chunk I2b (iou-hs t=6..11) -> buf1 : in flight under P4
    for (int u = tid; u < 1536; u += 256) gl_lds16(Bg + 4608 + u, Bs + 1536 + u);

    // P4: acc[0..5] hs-contribution from buf0
    __builtin_amdgcn_s_setprio(1);
    #pragma unroll
    for (int t = 0; t < 6; ++t) {
        #pragma unroll
        for (int s = 0; s < 2; ++s) {
            bf16x8 bh = Bs[((t * 2 + s) * 2 + 0) * 64 + l];
            bf16x8 bl = Bs[((t * 2 + s) * 2 + 1) * 64 + l];
            acc[t] = MFMA(sh[s], bh, acc[t]);
            acc[t] = MFMA(sh[s], bl, acc[t]);
            acc[t] = MFMA(sl[s], bh, acc[t]);
        }
    }
    __builtin_amdgcn_s_setprio(0);
    __syncthreads();                             // drains I2b

    // P5: acc[6..11] hs-contribution from buf1
    __builtin_amdgcn_s_setprio(1);
    #pragma unroll
    for (int t = 6; t < 12; ++t) {
        int tt = t - 6;
        #pragma unroll
        for (int s = 0; s < 2; ++s) {
            bf16x8 bh = Bs[1536 + ((tt * 2 + s) * 2 + 0) * 64 + l];
            bf16x8 bl = Bs[1536 + ((tt * 2 + s) * 2 + 1) * 64 + l];
            acc[t] = MFMA(sh[s], bh, acc[t]);
            acc[t] = MFMA(sh[s], bl, acc[t]);
            acc[t] = MFMA(sl[s], bh, acc[t]);
        }
    }
    __builtin_amdgcn_s_setprio(0);

    // Epilogue: lane-local gates; coalesced c-child reads per 16-lane group.
    float psum[4] = {0.f, 0.f, 0.f, 0.f};
    #pragma unroll
    for (int r = 0; r < 4; ++r) {
        int gr = base + (l >> 4) * 4 + r;
        int treer = gr >> lvl, ir = gr & (m - 1);
        int lr = (m - 1) + ir;
        int nr = treer * NPT + lr;
        size_t ch0 = (size_t)(treer * NPT + 2 * lr + 1) * H;
        size_t ch1 = ch0 + H;
        #pragma unroll
        for (int t = 0; t < 4; ++t) {
            int j = 16 * t + colb;
            float ai = acc[t][r]     + b_iou[j];
            float ao = acc[4 + t][r] + b_iou[64 + j];
            float au = acc[8 + t][r] + b_iou[128 + j];
            float cv = sigm(ai) * ftanh(au) + f0[t][r] * c[ch0 + j] + f1[t][r] * c[ch1 + j];
            float hval = sigm(ao) * ftanh(cv);
            c[(size_t)nr * H + j] = cv;
            h[(size_t)nr * H + j] = hval;
            psum[t] += hval;
        }
    }
    if (woff >= 0) store_partial(psum, l, woff + blockIdx.x * 4 + w, partw);
}

// ---- Fused small levels (lvl 3..0): 32 blocks x 512 threads, 16 trees/block,
// full 128KB B resident in dynamic LDS (staged once). One __syncthreads per
// level; same-block global h/c writes are visible after the barrier (same CU).
__global__ __launch_bounds__(512)
void small_levels(const float* __restrict__ feat, const unsigned short* __restrict__ Braw,
                  const float* __restrict__ b_iou, const float* __restrict__ b_f,
                  float* __restrict__ h, float* __restrict__ c)
{
    extern __shared__ bf16x8 Bs[];               // 8192 units = 128KB
    const bf16x8* Bg = (const bf16x8*)Braw;
    int tid = threadIdx.x;
    for (int u = tid; u < 8192; u += 512) gl_lds16(Bg + u, Bs + u);
    __syncthreads();

    int l    = tid & 63;
    int w    = tid >> 6;
    int colb = l & 15;
    int ko   = 8 * (l >> 4);

    for (int lvl = 3; lvl >= 0; --lvl) {
        if (w < (1 << lvl)) {
            int m     = 1 << lvl;
            int base  = blockIdx.x * (16 << lvl) + w * 16;
            int g     = base + colb;
            int tree  = g >> lvl, i = g & (m - 1);
            int local = (m - 1) + i;
            int nrow  = tree * NPT + local;
            int crow0 = tree * NPT + 2 * local + 1;

            const float* fb  = feat + (size_t)nrow * H + ko;
            float4 fr0 = *(const float4*)(fb);
            float4 fr1 = *(const float4*)(fb + 4);
            float4 fr2 = *(const float4*)(fb + 32);
            float4 fr3 = *(const float4*)(fb + 36);
            const float* h0b = h + (size_t)crow0 * H + ko;
            const float* h1b = h0b + H;
            float4 a00 = *(const float4*)(h0b);
            float4 a01 = *(const float4*)(h0b + 4);
            float4 a02 = *(const float4*)(h0b + 32);
            float4 a03 = *(const float4*)(h0b + 36);
            float4 a10 = *(const float4*)(h1b);
            float4 a11 = *(const float4*)(h1b + 4);
            float4 a12 = *(const float4*)(h1b + 32);
            float4 a13 = *(const float4*)(h1b + 36);

            bf16x8 fh[2], fl[2], sh[2], sl[2], zh[2], zl[2];
            { float v[8] = {fr0.x,fr0.y,fr0.z,fr0.w,fr1.x,fr1.y,fr1.z,fr1.w}; split8(v, fh[0], fl[0]); }
            { float v[8] = {fr2.x,fr2.y,fr2.z,fr2.w,fr3.x,fr3.y,fr3.z,fr3.w}; split8(v, fh[1], fl[1]); }
            {
                float v0[8] = {a00.x,a00.y,a00.z,a00.w,a01.x,a01.y,a01.z,a01.w};
                float v1[8] = {a10.x,a10.y,a10.z,a10.w,a11.x,a11.y,a11.z,a11.w};
                float vs[8];
                #pragma unroll
                for (int e = 0; e < 8; ++e) vs[e] = v0[e] + v1[e];
                split8(v0, zh[0], zl[0]); split8(vs, sh[0], sl[0]);
            }
            {
                float v0[8] = {a02.x,a02.y,a02.z,a02.w,a03.x,a03.y,a03.z,a03.w};
                float v1[8] = {a12.x,a12.y,a12.z,a12.w,a13.x,a13.y,a13.z,a13.w};
                float vs[8];
                #pragma unroll
                for (int e = 0; e < 8; ++e) vs[e] = v0[e] + v1[e];
                split8(v0, zh[1], zl[1]); split8(vs, sh[1], sl[1]);
            }

            // Phase F (resident chunk at unit 6144)
            float f0[4][4], f1[4][4];
            #pragma unroll
            for (int t = 0; t < 4; ++t) {
                f32x4 ax  = (f32x4){0.f,0.f,0.f,0.f};
                f32x4 as_ = (f32x4){0.f,0.f,0.f,0.f};
                f32x4 az  = (f32x4){0.f,0.f,0.f,0.f};
                #pragma unroll
                for (int s = 0; s < 2; ++s) {
                    int qb = (t * 2 + s) * 4;
                    bf16x8 bxh = Bs[6144 + (qb + 0) * 64 + l];
                    bf16x8 bxl = Bs[6144 + (qb + 1) * 64 + l];
                    bf16x8 buh = Bs[6144 + (qb + 2) * 64 + l];
                    bf16x8 bul = Bs[6144 + (qb + 3) * 64 + l];
                    ax  = MFMA(fh[s], bxh, ax);  ax  = MFMA(fh[s], bxl, ax);  ax  = MFMA(fl[s], bxh, ax);
                    as_ = MFMA(sh[s], buh, as_); as_ = MFMA(sh[s], bul, as_); as_ = MFMA(sl[s], buh, as_);
                    az  = MFMA(zh[s], buh, az);  az  = MFMA(zh[s], bul, az);  az  = MFMA(zl[s], buh, az);
                }
                #pragma unroll
                for (int r = 0; r < 4; ++r) {
                    float afx = ax[r] + b_f[16 * t + colb];
                    f0[t][r] = sigm(afx + az[r]);
                    f1[t][r] = sigm(afx + (as_[r] - az[r]));
                }
            }

            // Phase I.1 (x, resident chunk at 0) then I.2 (hs, chunk at 3072)
            f32x4 acc[12];
            #pragma unroll
            for (int t = 0; t < 12; ++t) acc[t] = (f32x4){0.f,0.f,0.f,0.f};
            #pragma unroll
            for (int t = 0; t < 12; ++t) {
                #pragma unroll
                for (int s = 0; s < 2; ++s) {
                    bf16x8 bh = Bs[((t * 2 + s) * 2 + 0) * 64 + l];
                    bf16x8 bl = Bs[((t * 2 + s) * 2 + 1) * 64 + l];
                    acc[t] = MFMA(fh[s], bh, acc[t]);
                    acc[t] = MFMA(fh[s], bl, acc[t]);
                    acc[t] = MFMA(fl[s], bh, acc[t]);
                }
            }
            #pragma unroll
            for (int t = 0; t < 12; ++t) {
                #pragma unroll
                for (int s = 0; s < 2; ++s) {
                    bf16x8 bh = Bs[3072 + ((t * 2 + s) * 2 + 0) * 64 + l];
                    bf16x8 bl = Bs[3072 + ((t * 2 + s) * 2 + 1) * 64 + l];
                    acc[t] = MFMA(sh[s], bh, acc[t]);
                    acc[t] = MFMA(sh[s], bl, acc[t]);
                    acc[t] = MFMA(sl[s], bh, acc[t]);
                }
            }

            // Epilogue
            #pragma unroll
            for (int r = 0; r < 4; ++r) {
                int gr = base + (l >> 4) * 4 + r;
                int treer = gr >> lvl, ir = gr & (m - 1);
                int lr = (m - 1) + ir;
                int nr = treer * NPT + lr;
                size_t ch0 = (size_t)(treer * NPT + 2 * lr + 1) * H;
                size_t ch1 = ch0 + H;
                #pragma unroll
                for (int t = 0; t < 4; ++t) {
                    int j = 16 * t + colb;
                    float ai = acc[t][r]     + b_iou[j];
                    float ao = acc[4 + t][r] + b_iou[64 + j];
                    float au = acc[8 + t][r] + b_iou[128 + j];
                    float cv = sigm(ai) * ftanh(au) + f0[t][r] * c[ch0 + j] + f1[t][r] * c[ch1 + j];
                    float hval = sigm(ao) * ftanh(cv);
                    c[(size_t)nr * H + j] = cv;
                    h[(size_t)nr * H + j] = hval;
                }
            }
        }
        __syncthreads();   // level boundary: all threads, every iteration
    }
}

// ---- Final: gather wave partials (levels 9..4) + h rows 0..14 (levels 3..0),
// mean -> relu -> 2-layer MLP -> out dot. One block (64 threads) per tree.
__global__ __launch_bounds__(64)
void final_mlp(const float* __restrict__ h, const float* __restrict__ partw,
               const float* __restrict__ l0w, const float* __restrict__ l0b,
               const float* __restrict__ l1w, const float* __restrict__ l1b,
               const float* __restrict__ ow,  const float* __restrict__ ob,
               float* __restrict__ out)
{
    int tree = blockIdx.x;
    int f = threadIdx.x;
    float s = 0.0f;
    #pragma unroll 4
    for (int k = 0; k < 32; ++k) s += partw[(size_t)(tree * 32 + k) * H + f];          // leaf
    #pragma unroll 4
    for (int k = 0; k < 16; ++k) s += partw[(size_t)(16384 + tree * 16 + k) * H + f];  // lvl8
    #pragma unroll
    for (int k = 0; k < 8; ++k)  s += partw[(size_t)(24576 + tree * 8 + k) * H + f];   // lvl7
    #pragma unroll
    for (int k = 0; k < 4; ++k)  s += partw[(size_t)(28672 + tree * 4 + k) * H + f];   // lvl6
    #pragma unroll
    for (int k = 0; k < 2; ++k)  s += partw[(size_t)(30720 + tree * 2 + k) * H + f];   // lvl5
    s += partw[(size_t)(31744 + tree) * H + f];                                        // lvl4
    const float* hb = h + (size_t)tree * NPT * H;
    #pragma unroll
    for (int i = 0; i < 15; ++i) s += hb[i * H + f];                                   // lvl3..0
    float x = fmaxf(s * (1.0f / 1023.0f), 0.0f);

    __shared__ float xb[H];
    __shared__ float yb[H];
    xb[f] = x;
    __syncthreads();
    float acc = l0b[f];
    #pragma unroll
    for (int k = 0; k < H; ++k) acc = fmaf(l0w[f * H + k], xb[k], acc);
    acc = fmaxf(acc, 0.0f);
    yb[f] = acc;
    __syncthreads();
    float acc2 = l1b[f];
    #pragma unroll
    for (int k = 0; k < H; ++k) acc2 = fmaf(l1w[f * H + k], yb[k], acc2);
    acc2 = fmaxf(acc2, 0.0f);
    float t = ow[f] * acc2;
    #pragma unroll
    for (int off = 32; off > 0; off >>= 1) t += __shfl_down(t, off);
    if (f == 0) out[tree] = t + ob[0];
}

// ---- Fallback path (ws too small for partials): standalone pool + mlp ----
__global__ __launch_bounds__(256)
void pool_kernel(const float* __restrict__ h, float* __restrict__ x)
{
    __shared__ float red[4][H];
    int tree = blockIdx.x;
    int f = threadIdx.x & 63;
    int seg = threadIdx.x >> 6;
    const float* basep = h + (size_t)tree * NPT * H;
    int i0 = seg * 256, i1 = i0 + 256; if (i1 > NPT) i1 = NPT;
    float s = 0.f;
    for (int i = i0; i < i1; ++i) s += basep[i * H + f];
    red[seg][f] = s;
    __syncthreads();
    if (seg == 0) {
        float tot = red[0][f] + red[1][f] + red[2][f] + red[3][f];
        x[tree * H + f] = fmaxf(tot * (1.0f / 1023.0f), 0.0f);
    }
}

__global__ __launch_bounds__(64)
void mlp_kernel(const float* __restrict__ x,
                const float* __restrict__ l0w, const float* __restrict__ l0b,
                const float* __restrict__ l1w, const float* __restrict__ l1b,
                const float* __restrict__ ow,  const float* __restrict__ ob,
                float* __restrict__ out)
{
    int tree = blockIdx.x;
    int j = threadIdx.x;
    __shared__ float xb[H];
    __shared__ float yb[H];
    xb[j] = x[tree * H + j];
    __syncthreads();
    float acc = l0b[j];
    #pragma unroll
    for (int k = 0; k < H; ++k) acc = fmaf(l0w[j * H + k], xb[k], acc);
    acc = fmaxf(acc, 0.0f);
    yb[j] = acc;
    __syncthreads();
    float acc2 = l1b[j];
    #pragma unroll
    for (int k = 0; k < H; ++k) acc2 = fmaf(l1w[j * H + k], yb[k], acc2);
    acc2 = fmaxf(acc2, 0.0f);
    float t = ow[j] * acc2;
    #pragma unroll
    for (int off = 32; off > 0; off >>= 1) t += __shfl_down(t, off);
    if (j == 0) out[tree] = t + ob[0];
}

extern "C" void kernel_launch(void* const* d_in, const int* in_sizes, int n_in,
                              void* d_out, int out_size, void* d_ws, size_t ws_size,
                              hipStream_t stream)
{
    const float* feat  = (const float*)d_in[0];
    // d_in[1..3]: node_order / adjacency / edge_order -- analytic heap structure, unused.
    const float* w_iou = (const float*)d_in[4];
    const float* b_iou = (const float*)d_in[5];
    const float* u_iou = (const float*)d_in[6];
    const float* w_f   = (const float*)d_in[7];
    const float* b_f   = (const float*)d_in[8];
    const float* u_f   = (const float*)d_in[9];
    const float* l0w   = (const float*)d_in[10];
    const float* l0b   = (const float*)d_in[11];
    const float* l1w   = (const float*)d_in[12];
    const float* l1b   = (const float*)d_in[13];
    const float* ow    = (const float*)d_in[14];
    const float* ob    = (const float*)d_in[15];
    float* out = (float*)d_out;

    // ws: h[NTOT*H] f32 | c[NTOT*H] f32 | x[NTREES*H] f32 | Bf(128KB) | partw(8.26MB)
    float* h = (float*)d_ws;
    float* c = h + (size_t)NTOT * H;
    float* x = c + (size_t)NTOT * H;
    unsigned short* Bf = (unsigned short*)(x + NTREES * H);
    float* partw = (float*)(Bf + 65536);
    size_t needed = (size_t)((char*)(partw + (size_t)PART_SLOTS * H) - (char*)d_ws);
    int use_part = (ws_size >= needed) ? 1 : 0;

    // opt-in for 128KB dynamic LDS (idempotent, capture-safe -- proven in R7/R11)
    hipFuncSetAttribute(reinterpret_cast<const void*>(small_levels),
                        hipFuncAttributeMaxDynamicSharedMemorySize, 131072);

    prep_b<<<256, 256, 0, stream>>>(w_iou, u_iou, w_f, u_f, Bf);
    leaf_mfma<<<4096, 256, 0, stream>>>(feat, Bf, b_iou, h, c, partw, use_part);
    for (int lvl = DEPTH - 2; lvl >= 4; --lvl) {
        int woff = (use_part) ? (32768 - (64 << lvl)) : -1;
        internal_mfma<<<8 << lvl, 256, 0, stream>>>(
            feat, Bf, b_iou, b_f, h, c, lvl, partw, woff);
    }
    small_levels<<<32, 512, 131072, stream>>>(feat, Bf, b_iou, b_f, h, c);
    if (use_part) {
        final_mlp<<<NTREES, 64, 0, stream>>>(h, partw, l0w, l0b, l1w, l1b, ow, ob, out);
    } else {
        pool_kernel<<<NTREES, 256, 0, stream>>>(h, x);
        mlp_kernel<<<NTREES, 64, 0, stream>>>(x, l0w, l0b, l1w, l1b, ow, ob, out);
    }
}

// Round 15
// 266.778 us; speedup vs baseline: 1.0149x; 1.0149x over previous
//
#include <hip/hip_runtime.h>
#include <math.h>

#define NTREES 512
#define DEPTH  10
#define NPT    1023
#define NTOT   (NTREES * NPT)   // 523776
#define H      64
#define PART_SLOTS 32256        // wave partials for levels 9(leaf)..4

typedef __attribute__((ext_vector_type(8))) short bf16x8;
typedef __attribute__((ext_vector_type(4))) float f32x4;

// v_rcp_f32 (1-ulp approx) instead of IEEE divide: saves ~14 VALU inst per gate.
__device__ __forceinline__ float sigm(float x)  { return __builtin_amdgcn_rcpf(1.0f + __expf(-x)); }
__device__ __forceinline__ float ftanh(float x) { return fmaf(-2.0f, __builtin_amdgcn_rcpf(__expf(2.0f * x) + 1.0f), 1.0f); }

__device__ __forceinline__ unsigned short bf_hi(float f) {
    unsigned u = __float_as_uint(f);
    return (unsigned short)((u + 0x7fffu + ((u >> 16) & 1u)) >> 16);
}
__device__ __forceinline__ float bf_f(unsigned short h) {
    return __uint_as_float(((unsigned)h) << 16);
}
__device__ __forceinline__ void split8(const float v[8], bf16x8& hi, bf16x8& lo) {
    #pragma unroll
    for (int e = 0; e < 8; ++e) {
        unsigned short hh = bf_hi(v[e]);
        hi[e] = (short)hh;
        lo[e] = (short)bf_hi(v[e] - bf_f(hh));
    }
}

#define MFMA(a, b, c) __builtin_amdgcn_mfma_f32_16x16x32_bf16((a), (b), (c), 0, 0, 0)

// Direct global->LDS DMA, 16B per lane. Dest pattern is per-wave linear
// (uniform base + lane*16), which is the HW-supported layout. The following
// __syncthreads() drains vmcnt for these loads.
__device__ __forceinline__ void gl_lds16(const void* g, void* s) {
    __builtin_amdgcn_global_load_lds(
        (const __attribute__((address_space(1))) unsigned*)g,
        (__attribute__((address_space(3))) unsigned*)s, 16, 0, 0);
}

// ---- B prep (layout unchanged from rounds 3..13) ----
__global__ void prep_b(const float* __restrict__ w_iou, const float* __restrict__ u_iou,
                       const float* __restrict__ w_f,  const float* __restrict__ u_f,
                       unsigned short* __restrict__ B)
{
    int idx  = blockIdx.x * 256 + threadIdx.x;   // 0..65535
    int unit = idx >> 3;
    int e    = idx & 7;
    int l    = unit & 63;
    float v;
    int hl;
    if (unit < 6144) {
        int sp = (unit >= 3072) ? 1 : 0;
        int r  = unit - sp * 3072;
        int q  = r >> 6;
        hl     = q & 1;
        int ts = q >> 1;
        int s_ = ts & 1;
        int t  = ts >> 1;
        int s  = sp * 2 + s_;
        int col = t * 16 + (l & 15);
        int k   = 32 * s + 8 * (l >> 4) + e;
        v = (k < 64) ? w_iou[col * H + k] : u_iou[col * H + (k - 64)];
    } else {
        int r  = unit - 6144;
        int q  = r >> 6;
        hl     = q & 1;
        int xu = (q >> 1) & 1;
        int ts = q >> 2;
        int s  = ts & 1;
        int t  = ts >> 1;
        int col = t * 16 + (l & 15);
        int k   = 32 * s + 8 * (l >> 4) + e;
        v = xu ? u_f[col * H + k] : w_f[col * H + k];
    }
    unsigned short hv = bf_hi(v);
    B[idx] = hl ? bf_hi(v - bf_f(hv)) : hv;
}

// Per-wave pooling partial: psum[t] summed across the four 16-lane groups.
__device__ __forceinline__ void store_partial(float psum[4], int l, int wid,
                                              float* __restrict__ partw)
{
    #pragma unroll
    for (int t = 0; t < 4; ++t) {
        float v = psum[t];
        v += __shfl_xor(v, 16);
        v += __shfl_xor(v, 32);
        if (l < 16) partw[(size_t)wid * H + 16 * t + l] = v;
    }
}

// ---- Leaves: 4 waves/block, 16 nodes/wave; iou-x chunk staged in LDS
// via global_load_lds; setprio(1) around the MFMA cluster.
__global__ __launch_bounds__(256, 3)
void leaf_mfma(const float* __restrict__ feat, const unsigned short* __restrict__ Braw,
               const float* __restrict__ b_iou,
               float* __restrict__ h, float* __restrict__ c,
               float* __restrict__ partw, int do_part)
{
    __shared__ bf16x8 Bs[3072];                  // 48KB
    int tid = threadIdx.x;
    int l   = tid & 63;
    int w   = tid >> 6;
    int base = blockIdx.x * 64 + w * 16;
    int g    = base + (l & 15);
    int nrow = (g >> 9) * NPT + 511 + (g & 511);
    int ko   = 8 * (l >> 4);

    const float* fb = feat + (size_t)nrow * H + ko;
    float4 fr0 = *(const float4*)(fb);
    float4 fr1 = *(const float4*)(fb + 4);
    float4 fr2 = *(const float4*)(fb + 32);
    float4 fr3 = *(const float4*)(fb + 36);

    const bf16x8* Bg = (const bf16x8*)Braw;
    for (int u = tid; u < 3072; u += 256) gl_lds16(Bg + u, Bs + u);
    __syncthreads();

    bf16x8 fh[2], fl[2];
    { float v[8] = {fr0.x,fr0.y,fr0.z,fr0.w,fr1.x,fr1.y,fr1.z,fr1.w}; split8(v, fh[0], fl[0]); }
    { float v[8] = {fr2.x,fr2.y,fr2.z,fr2.w,fr3.x,fr3.y,fr3.z,fr3.w}; split8(v, fh[1], fl[1]); }

    f32x4 acc[12];
    #pragma unroll
    for (int t = 0; t < 12; ++t) acc[t] = (f32x4){0.f,0.f,0.f,0.f};
    __builtin_amdgcn_s_setprio(1);
    #pragma unroll
    for (int t = 0; t < 12; ++t) {
        #pragma unroll
        for (int s = 0; s < 2; ++s) {
            bf16x8 bh = Bs[((t * 2 + s) * 2 + 0) * 64 + l];
            bf16x8 bl = Bs[((t * 2 + s) * 2 + 1) * 64 + l];
            acc[t] = MFMA(fh[s], bh, acc[t]);
            acc[t] = MFMA(fh[s], bl, acc[t]);
            acc[t] = MFMA(fl[s], bh, acc[t]);
        }
    }
    __builtin_amdgcn_s_setprio(0);
    int colb = l & 15;
    float psum[4] = {0.f, 0.f, 0.f, 0.f};
    #pragma unroll
    for (int r = 0; r < 4; ++r) {
        int gr = base + (l >> 4) * 4 + r;
        int nr = (gr >> 9) * NPT + 511 + (gr & 511);
        #pragma unroll
        for (int t = 0; t < 4; ++t) {
            int j = 16 * t + colb;
            float ai = acc[t][r]     + b_iou[j];
            float ao = acc[4 + t][r] + b_iou[64 + j];
            float au = acc[8 + t][r] + b_iou[128 + j];
            float cv = sigm(ai) * ftanh(au);
            float hval = sigm(ao) * ftanh(cv);
            c[(size_t)nr * H + j] = cv;
            h[(size_t)nr * H + j] = hval;
            psum[t] += hval;
        }
    }
    if (do_part) store_partial(psum, l, blockIdx.x * 4 + w, partw);
}

// ---- Internal levels (lvl 8..4): 4 waves/block, 16 nodes/wave; B staged through
// 48KB LDS in 3 chunks via global_load_lds; setprio around MFMA clusters.
__global__ __launch_bounds__(256, 3)
void internal_mfma(const float* __restrict__ feat, const unsigned short* __restrict__ Braw,
                   const float* __restrict__ b_iou, const float* __restrict__ b_f,
                   float* __restrict__ h, float* __restrict__ c, int lvl,
                   float* __restrict__ partw, int woff)
{
    __shared__ bf16x8 Bs[3072];                  // 48KB
    int tid = threadIdx.x;
    int l   = tid & 63;
    int w   = tid >> 6;
    int m   = 1 << lvl;
    int base  = blockIdx.x * 64 + w * 16;
    int g     = base + (l & 15);
    int tree  = g >> lvl, i = g & (m - 1);
    int local = (m - 1) + i;
    int nrow  = tree * NPT + local;
    int crow0 = tree * NPT + 2 * local + 1;
    int ko    = 8 * (l >> 4);
    int colb  = l & 15;

    // issue all A loads first; latency hides under staging + barrier
    const float* fb  = feat + (size_t)nrow * H + ko;
    float4 fr0 = *(const float4*)(fb);
    float4 fr1 = *(const float4*)(fb + 4);
    float4 fr2 = *(const float4*)(fb + 32);
    float4 fr3 = *(const float4*)(fb + 36);
    const float* h0b = h + (size_t)crow0 * H + ko;
    const float* h1b = h0b + H;
    float4 a00 = *(const float4*)(h0b);
    float4 a01 = *(const float4*)(h0b + 4);
    float4 a02 = *(const float4*)(h0b + 32);
    float4 a03 = *(const float4*)(h0b + 36);
    float4 a10 = *(const float4*)(h1b);
    float4 a11 = *(const float4*)(h1b + 4);
    float4 a12 = *(const float4*)(h1b + 32);
    float4 a13 = *(const float4*)(h1b + 36);

    const bf16x8* Bg = (const bf16x8*)Braw;
    for (int u = tid; u < 2048; u += 256) gl_lds16(Bg + 6144 + u, Bs + u);  // forget chunk
    __syncthreads();

    bf16x8 fh[2], fl[2], sh[2], sl[2], zh[2], zl[2];
    { float v[8] = {fr0.x,fr0.y,fr0.z,fr0.w,fr1.x,fr1.y,fr1.z,fr1.w}; split8(v, fh[0], fl[0]); }
    { float v[8] = {fr2.x,fr2.y,fr2.z,fr2.w,fr3.x,fr3.y,fr3.z,fr3.w}; split8(v, fh[1], fl[1]); }
    {
        float v0[8] = {a00.x,a00.y,a00.z,a00.w,a01.x,a01.y,a01.z,a01.w};
        float v1[8] = {a10.x,a10.y,a10.z,a10.w,a11.x,a11.y,a11.z,a11.w};
        float vs[8];
        #pragma unroll
        for (int e = 0; e < 8; ++e) vs[e] = v0[e] + v1[e];
        split8(v0, zh[0], zl[0]); split8(vs, sh[0], sl[0]);
    }
    {
        float v0[8] = {a02.x,a02.y,a02.z,a02.w,a03.x,a03.y,a03.z,a03.w};
        float v1[8] = {a12.x,a12.y,a12.z,a12.w,a13.x,a13.y,a13.z,a13.w};
        float vs[8];
        #pragma unroll
        for (int e = 0; e < 8; ++e) vs[e] = v0[e] + v1[e];
        split8(v0, zh[1], zl[1]); split8(vs, sh[1], sl[1]);
    }

    // Phase F: forget gates (afx, af_sum, af_h0)
    float f0[4][4], f1[4][4];
    __builtin_amdgcn_s_setprio(1);
    #pragma unroll
    for (int t = 0; t < 4; ++t) {
        f32x4 ax  = (f32x4){0.f,0.f,0.f,0.f};
        f32x4 as_ = (f32x4){0.f,0.f,0.f,0.f};
        f32x4 az  = (f32x4){0.f,0.f,0.f,0.f};
        #pragma unroll
        for (int s = 0; s < 2; ++s) {
            int qb = (t * 2 + s) * 4;
            bf16x8 bxh = Bs[(qb + 0) * 64 + l];
            bf16x8 bxl = Bs[(qb + 1) * 64 + l];
            bf16x8 buh = Bs[(qb + 2) * 64 + l];
            bf16x8 bul = Bs[(qb + 3) * 64 + l];
            ax  = MFMA(fh[s], bxh, ax);  ax  = MFMA(fh[s], bxl, ax);  ax  = MFMA(fl[s], bxh, ax);
            as_ = MFMA(sh[s], buh, as_); as_ = MFMA(sh[s], bul, as_); as_ = MFMA(sl[s], buh, as_);
            az  = MFMA(zh[s], buh, az);  az  = MFMA(zh[s], bul, az);  az  = MFMA(zl[s], buh, az);
        }
        #pragma unroll
        for (int r = 0; r < 4; ++r) {
            float afx = ax[r] + b_f[16 * t + colb];
            f0[t][r] = sigm(afx + az[r]);
            f1[t][r] = sigm(afx + (as_[r] - az[r]));
        }
    }
    __builtin_amdgcn_s_setprio(0);
    __syncthreads();

    // Phase I.1: iou over x
    for (int u = tid; u < 3072; u += 256) gl_lds16(Bg + u, Bs + u);
    __syncthreads();
    f32x4 acc[12];
    #pragma unroll
    for (int t = 0; t < 12; ++t) acc[t] = (f32x4){0.f,0.f,0.f,0.f};
    __builtin_amdgcn_s_setprio(1);
    #pragma unroll
    for (int t = 0; t < 12; ++t) {
        #pragma unroll
        for (int s = 0; s < 2; ++s) {
            bf16x8 bh = Bs[((t * 2 + s) * 2 + 0) * 64 + l];
            bf16x8 bl = Bs[((t * 2 + s) * 2 + 1) * 64 + l];
            acc[t] = MFMA(fh[s], bh, acc[t]);
            acc[t] = MFMA(fh[s], bl, acc[t]);
            acc[t] = MFMA(fl[s], bh, acc[t]);
        }
    }
    __builtin_amdgcn_s_setprio(0);
    __syncthreads();

    // Phase I.2: iou over hs
    for (int u = tid; u < 3072; u += 256) gl_lds16(Bg + 3072 + u, Bs + u);
    __syncthreads();
    __builtin_amdgcn_s_setprio(1);
    #pragma unroll
    for (int t = 0; t < 12; ++t) {
        #pragma unroll
        for (int s = 0; s < 2; ++s) {
            bf16x8 bh = Bs[((t * 2 + s) * 2 + 0) * 64 + l];
            bf16x8 bl = Bs[((t * 2 + s) * 2 + 1) * 64 + l];
            acc[t] = MFMA(sh[s], bh, acc[t]);
            acc[t] = MFMA(sh[s], bl, acc[t]);
            acc[t] = MFMA(sl[s], bh, acc[t]);
        }
    }
    __builtin_amdgcn_s_setprio(0);

    // Epilogue: lane-local gates; coalesced c-child reads per 16-lane group.
    float psum[4] = {0.f, 0.f, 0.f, 0.f};
    #pragma unroll
    for (int r = 0; r < 4; ++r) {
        int gr = base + (l >> 4) * 4 + r;
        int treer = gr >> lvl, ir = gr & (m - 1);
        int lr = (m - 1) + ir;
        int nr = treer * NPT + lr;
        size_t ch0 = (size_t)(treer * NPT + 2 * lr + 1) * H;
        size_t ch1 = ch0 + H;
        #pragma unroll
        for (int t = 0; t < 4; ++t) {
            int j = 16 * t + colb;
            float ai = acc[t][r]     + b_iou[j];
            float ao = acc[4 + t][r] + b_iou[64 + j];
            float au = acc[8 + t][r] + b_iou[128 + j];
            float cv = sigm(ai) * ftanh(au) + f0[t][r] * c[ch0 + j] + f1[t][r] * c[ch1 + j];
            float hval = sigm(ao) * ftanh(cv);
            c[(size_t)nr * H + j] = cv;
            h[(size_t)nr * H + j] = hval;
            psum[t] += hval;
        }
    }
    if (woff >= 0) store_partial(psum, l, woff + blockIdx.x * 4 + w, partw);
}

// ---- Fused small levels (lvl 3..0): 32 blocks x 512 threads, 16 trees/block,
// full 128KB B resident in dynamic LDS (staged once). One __syncthreads per
// level; same-block global h/c writes are visible after the barrier (same CU).
__global__ __launch_bounds__(512)
void small_levels(const float* __restrict__ feat, const unsigned short* __restrict__ Braw,
                  const float* __restrict__ b_iou, const float* __restrict__ b_f,
                  float* __restrict__ h, float* __restrict__ c)
{
    extern __shared__ bf16x8 Bs[];               // 8192 units = 128KB
    const bf16x8* Bg = (const bf16x8*)Braw;
    int tid = threadIdx.x;
    for (int u = tid; u < 8192; u += 512) gl_lds16(Bg + u, Bs + u);
    __syncthreads();

    int l    = tid & 63;
    int w    = tid >> 6;
    int colb = l & 15;
    int ko   = 8 * (l >> 4);

    for (int lvl = 3; lvl >= 0; --lvl) {
        if (w < (1 << lvl)) {
            int m     = 1 << lvl;
            int base  = blockIdx.x * (16 << lvl) + w * 16;
            int g     = base + colb;
            int tree  = g >> lvl, i = g & (m - 1);
            int local = (m - 1) + i;
            int nrow  = tree * NPT + local;
            int crow0 = tree * NPT + 2 * local + 1;

            const float* fb  = feat + (size_t)nrow * H + ko;
            float4 fr0 = *(const float4*)(fb);
            float4 fr1 = *(const float4*)(fb + 4);
            float4 fr2 = *(const float4*)(fb + 32);
            float4 fr3 = *(const float4*)(fb + 36);
            const float* h0b = h + (size_t)crow0 * H + ko;
            const float* h1b = h0b + H;
            float4 a00 = *(const float4*)(h0b);
            float4 a01 = *(const float4*)(h0b + 4);
            float4 a02 = *(const float4*)(h0b + 32);
            float4 a03 = *(const float4*)(h0b + 36);
            float4 a10 = *(const float4*)(h1b);
            float4 a11 = *(const float4*)(h1b + 4);
            float4 a12 = *(const float4*)(h1b + 32);
            float4 a13 = *(const float4*)(h1b + 36);

            bf16x8 fh[2], fl[2], sh[2], sl[2], zh[2], zl[2];
            { float v[8] = {fr0.x,fr0.y,fr0.z,fr0.w,fr1.x,fr1.y,fr1.z,fr1.w}; split8(v, fh[0], fl[0]); }
            { float v[8] = {fr2.x,fr2.y,fr2.z,fr2.w,fr3.x,fr3.y,fr3.z,fr3.w}; split8(v, fh[1], fl[1]); }
            {
                float v0[8] = {a00.x,a00.y,a00.z,a00.w,a01.x,a01.y,a01.z,a01.w};
                float v1[8] = {a10.x,a10.y,a10.z,a10.w,a11.x,a11.y,a11.z,a11.w};
                float vs[8];
                #pragma unroll
                for (int e = 0; e < 8; ++e) vs[e] = v0[e] + v1[e];
                split8(v0, zh[0], zl[0]); split8(vs, sh[0], sl[0]);
            }
            {
                float v0[8] = {a02.x,a02.y,a02.z,a02.w,a03.x,a03.y,a03.z,a03.w};
                float v1[8] = {a12.x,a12.y,a12.z,a12.w,a13.x,a13.y,a13.z,a13.w};
                float vs[8];
                #pragma unroll
                for (int e = 0; e < 8; ++e) vs[e] = v0[e] + v1[e];
                split8(v0, zh[1], zl[1]); split8(vs, sh[1], sl[1]);
            }

            // Phase F (resident chunk at unit 6144)
            float f0[4][4], f1[4][4];
            #pragma unroll
            for (int t = 0; t < 4; ++t) {
                f32x4 ax  = (f32x4){0.f,0.f,0.f,0.f};
                f32x4 as_ = (f32x4){0.f,0.f,0.f,0.f};
                f32x4 az  = (f32x4){0.f,0.f,0.f,0.f};
                #pragma unroll
                for (int s = 0; s < 2; ++s) {
                    int qb = (t * 2 + s) * 4;
                    bf16x8 bxh = Bs[6144 + (qb + 0) * 64 + l];
                    bf16x8 bxl = Bs[6144 + (qb + 1) * 64 + l];
                    bf16x8 buh = Bs[6144 + (qb + 2) * 64 + l];
                    bf16x8 bul = Bs[6144 + (qb + 3) * 64 + l];
                    ax  = MFMA(fh[s], bxh, ax);  ax  = MFMA(fh[s], bxl, ax);  ax  = MFMA(fl[s], bxh, ax);
                    as_ = MFMA(sh[s], buh, as_); as_ = MFMA(sh[s], bul, as_); as_ = MFMA(sl[s], buh, as_);
                    az  = MFMA(zh[s], buh, az);  az  = MFMA(zh[s], bul, az);  az  = MFMA(zl[s], buh, az);
                }
                #pragma unroll
                for (int r = 0; r < 4; ++r) {
                    float afx = ax[r] + b_f[16 * t + colb];
                    f0[t][r] = sigm(afx + az[r]);
                    f1[t][r] = sigm(afx + (as_[r] - az[r]));
                }
            }

            // Phase I.1 (x, resident chunk at 0) then I.2 (hs, chunk at 3072)
            f32x4 acc[12];
            #pragma unroll
            for (int t = 0; t < 12; ++t) acc[t] = (f32x4){0.f,0.f,0.f,0.f};
            #pragma unroll
            for (int t = 0; t < 12; ++t) {
                #pragma unroll
                for (int s = 0; s < 2; ++s) {
                    bf16x8 bh = Bs[((t * 2 + s) * 2 + 0) * 64 + l];
                    bf16x8 bl = Bs[((t * 2 + s) * 2 + 1) * 64 + l];
                    acc[t] = MFMA(fh[s], bh, acc[t]);
                    acc[t] = MFMA(fh[s], bl, acc[t]);
                    acc[t] = MFMA(fl[s], bh, acc[t]);
                }
            }
            #pragma unroll
            for (int t = 0; t < 12; ++t) {
                #pragma unroll
                for (int s = 0; s < 2; ++s) {
                    bf16x8 bh = Bs[3072 + ((t * 2 + s) * 2 + 0) * 64 + l];
                    bf16x8 bl = Bs[3072 + ((t * 2 + s) * 2 + 1) * 64 + l];
                    acc[t] = MFMA(sh[s], bh, acc[t]);
                    acc[t] = MFMA(sh[s], bl, acc[t]);
                    acc[t] = MFMA(sl[s], bh, acc[t]);
                }
            }

            // Epilogue
            #pragma unroll
            for (int r = 0; r < 4; ++r) {
                int gr = base + (l >> 4) * 4 + r;
                int treer = gr >> lvl, ir = gr & (m - 1);
                int lr = (m - 1) + ir;
                int nr = treer * NPT + lr;
                size_t ch0 = (size_t)(treer * NPT + 2 * lr + 1) * H;
                size_t ch1 = ch0 + H;
                #pragma unroll
                for (int t = 0; t < 4; ++t) {
                    int j = 16 * t + colb;
                    float ai = acc[t][r]     + b_iou[j];
                    float ao = acc[4 + t][r] + b_iou[64 + j];
                    float au = acc[8 + t][r] + b_iou[128 + j];
                    float cv = sigm(ai) * ftanh(au) + f0[t][r] * c[ch0 + j] + f1[t][r] * c[ch1 + j];
                    float hval = sigm(ao) * ftanh(cv);
                    c[(size_t)nr * H + j] = cv;
                    h[(size_t)nr * H + j] = hval;
                }
            }
        }
        __syncthreads();   // level boundary: all threads, every iteration
    }
}

// ---- Final: gather wave partials (levels 9..4) + h rows 0..14 (levels 3..0),
// mean -> relu -> 2-layer MLP -> out dot. One block (64 threads) per tree.
__global__ __launch_bounds__(64)
void final_mlp(const float* __restrict__ h, const float* __restrict__ partw,
               const float* __restrict__ l0w, const float* __restrict__ l0b,
               const float* __restrict__ l1w, const float* __restrict__ l1b,
               const float* __restrict__ ow,  const float* __restrict__ ob,
               float* __restrict__ out)
{
    int tree = blockIdx.x;
    int f = threadIdx.x;
    float s = 0.0f;
    #pragma unroll 4
    for (int k = 0; k < 32; ++k) s += partw[(size_t)(tree * 32 + k) * H + f];          // leaf
    #pragma unroll 4
    for (int k = 0; k < 16; ++k) s += partw[(size_t)(16384 + tree * 16 + k) * H + f];  // lvl8
    #pragma unroll
    for (int k = 0; k < 8; ++k)  s += partw[(size_t)(24576 + tree * 8 + k) * H + f];   // lvl7
    #pragma unroll
    for (int k = 0; k < 4; ++k)  s += partw[(size_t)(28672 + tree * 4 + k) * H + f];   // lvl6
    #pragma unroll
    for (int k = 0; k < 2; ++k)  s += partw[(size_t)(30720 + tree * 2 + k) * H + f];   // lvl5
    s += partw[(size_t)(31744 + tree) * H + f];                                        // lvl4
    const float* hb = h + (size_t)tree * NPT * H;
    #pragma unroll
    for (int i = 0; i < 15; ++i) s += hb[i * H + f];                                   // lvl3..0
    float x = fmaxf(s * (1.0f / 1023.0f), 0.0f);

    __shared__ float xb[H];
    __shared__ float yb[H];
    xb[f] = x;
    __syncthreads();
    float acc = l0b[f];
    #pragma unroll
    for (int k = 0; k < H; ++k) acc = fmaf(l0w[f * H + k], xb[k], acc);
    acc = fmaxf(acc, 0.0f);
    yb[f] = acc;
    __syncthreads();
    float acc2 = l1b[f];
    #pragma unroll
    for (int k = 0; k < H; ++k) acc2 = fmaf(l1w[f * H + k], yb[k], acc2);
    acc2 = fmaxf(acc2, 0.0f);
    float t = ow[f] * acc2;
    #pragma unroll
    for (int off = 32; off > 0; off >>= 1) t += __shfl_down(t, off);
    if (f == 0) out[tree] = t + ob[0];
}

// ---- Fallback path (ws too small for partials): standalone pool + mlp ----
__global__ __launch_bounds__(256)
void pool_kernel(const float* __restrict__ h, float* __restrict__ x)
{
    __shared__ float red[4][H];
    int tree = blockIdx.x;
    int f = threadIdx.x & 63;
    int seg = threadIdx.x >> 6;
    const float* basep = h + (size_t)tree * NPT * H;
    int i0 = seg * 256, i1 = i0 + 256; if (i1 > NPT) i1 = NPT;
    float s = 0.f;
    for (int i = i0; i < i1; ++i) s += basep[i * H + f];
    red[seg][f] = s;
    __syncthreads();
    if (seg == 0) {
        float tot = red[0][f] + red[1][f] + red[2][f] + red[3][f];
        x[tree * H + f] = fmaxf(tot * (1.0f / 1023.0f), 0.0f);
    }
}

__global__ __launch_bounds__(64)
void mlp_kernel(const float* __restrict__ x,
                const float* __restrict__ l0w, const float* __restrict__ l0b,
                const float* __restrict__ l1w, const float* __restrict__ l1b,
                const float* __restrict__ ow,  const float* __restrict__ ob,
                float* __restrict__ out)
{
    int tree = blockIdx.x;
    int j = threadIdx.x;
    __shared__ float xb[H];
    __shared__ float yb[H];
    xb[j] = x[tree * H + j];
    __syncthreads();
    float acc = l0b[j];
    #pragma unroll
    for (int k = 0; k < H; ++k) acc = fmaf(l0w[j * H + k], xb[k], acc);
    acc = fmaxf(acc, 0.0f);
    yb[j] = acc;
    __syncthreads();
    float acc2 = l1b[j];
    #pragma unroll
    for (int k = 0; k < H; ++k) acc2 = fmaf(l1w[j * H + k], yb[k], acc2);
    acc2 = fmaxf(acc2, 0.0f);
    float t = ow[j] * acc2;
    #pragma unroll
    for (int off = 32; off > 0; off >>= 1) t += __shfl_down(t, off);
    if (j == 0) out[tree] = t + ob[0];
}

extern "C" void kernel_launch(void* const* d_in, const int* in_sizes, int n_in,
                              void* d_out, int out_size, void* d_ws, size_t ws_size,
                              hipStream_t stream)
{
    const float* feat  = (const float*)d_in[0];
    // d_in[1..3]: node_order / adjacency / edge_order -- analytic heap structure, unused.
    const float* w_iou = (const float*)d_in[4];
    const float* b_iou = (const float*)d_in[5];
    const float* u_iou = (const float*)d_in[6];
    const float* w_f   = (const float*)d_in[7];
    const float* b_f   = (const float*)d_in[8];
    const float* u_f   = (const float*)d_in[9];
    const float* l0w   = (const float*)d_in[10];
    const float* l0b   = (const float*)d_in[11];
    const float* l1w   = (const float*)d_in[12];
    const float* l1b   = (const float*)d_in[13];
    const float* ow    = (const float*)d_in[14];
    const float* ob    = (const float*)d_in[15];
    float* out = (float*)d_out;

    // ws: h[NTOT*H] f32 | c[NTOT*H] f32 | x[NTREES*H] f32 | Bf(128KB) | partw(8.26MB)
    float* h = (float*)d_ws;
    float* c = h + (size_t)NTOT * H;
    float* x = c + (size_t)NTOT * H;
    unsigned short* Bf = (unsigned short*)(x + NTREES * H);
    float* partw = (float*)(Bf + 65536);
    size_t needed = (size_t)((char*)(partw + (size_t)PART_SLOTS * H) - (char*)d_ws);
    int use_part = (ws_size >= needed) ? 1 : 0;

    // opt-in for 128KB dynamic LDS (idempotent, capture-safe -- proven in R7/R11)
    hipFuncSetAttribute(reinterpret_cast<const void*>(small_levels),
                        hipFuncAttributeMaxDynamicSharedMemorySize, 131072);

    prep_b<<<256, 256, 0, stream>>>(w_iou, u_iou, w_f, u_f, Bf);
    leaf_mfma<<<4096, 256, 0, stream>>>(feat, Bf, b_iou, h, c, partw, use_part);
    for (int lvl = DEPTH - 2; lvl >= 4; --lvl) {
        int woff = (use_part) ? (32768 - (64 << lvl)) : -1;
        internal_mfma<<<8 << lvl, 256, 0, stream>>>(
            feat, Bf, b_iou, b_f, h, c, lvl, partw, woff);
    }
    small_levels<<<32, 512, 131072, stream>>>(feat, Bf, b_iou, b_f, h, c);
    if (use_part) {
        final_mlp<<<NTREES, 64, 0, stream>>>(h, partw, l0w, l0b, l1w, l1b, ow, ob, out);
    } else {
        pool_kernel<<<NTREES, 256, 0, stream>>>(h, x);
        mlp_kernel<<<NTREES, 64, 0, stream>>>(x, l0w, l0b, l1w, l1b, ow, ob, out);
    }
}